// Round 3
// baseline (335.317 us; speedup 1.0000x reference)
//
#include <hip/hip_runtime.h>
#include <hip/hip_bf16.h>

// Inputs are FLOAT32 (per reference file): fm [64][768][676], att_w [192][768],
// att_b [192], fc_w [200][24576], fc_b [200].
// d_out (f32): p [64*200] | fm_n [64*32*768] | att_m [64*32*676]
// ws: att_pad bf16 [64][32][704] | pooled f32 [64][32][768] |
//     p_part f32 [16][64][208]   | fmn16 bf16 [64][32][768]
// MFMA runs in bf16 (no f32 MFMA on CDNA4); f32->bf16 RNE in-register.
// 2% abs threshold (0.1475 on p) leaves ~10x margin over bf16-product error.

typedef unsigned short u16;
typedef __bf16 bf16x8_t __attribute__((ext_vector_type(8)));
typedef float f32x4_t __attribute__((ext_vector_type(4)));
typedef unsigned int uint32x4 __attribute__((ext_vector_type(4)));

union Frag {
    uint32x4 u4;
    unsigned u[4];
    u16      s[8];
    bf16x8_t v;
};
union BFU { __hip_bfloat16 h; u16 u; };

__device__ inline u16 f2b(float x) { BFU t; t.h = __float2bfloat16(x); return t.u; }

// load 8 contiguous f32 (32B, two float4) and convert to a bf16 fragment
__device__ inline void load8_cvt(const float* p, Frag& f) {
    f32x4_t x0 = *(const f32x4_t*)(p);
    f32x4_t x1 = *(const f32x4_t*)(p + 4);
#pragma unroll
    for (int j = 0; j < 4; ++j) { f.s[j] = f2b(x0[j]); f.s[4 + j] = f2b(x1[j]); }
}

#define MFMA(a, b, c) __builtin_amdgcn_mfma_f32_16x16x32_bf16((a), (b), (c), 0, 0, 0)

// ---------------- Pass 1: att = relu(att_w[:32] @ fm[b] + att_b) ----------------
// grid (11 p-tiles, 64 b), 256 thr. Out tile 32 m x 64 p. Wave w: cols [w*16, w*16+16).
__global__ __launch_bounds__(256) void k_att(
    const float* __restrict__ fm, const float* __restrict__ att_w,
    const float* __restrict__ att_b,
    float* __restrict__ att_out, __hip_bfloat16* __restrict__ att_pad)
{
    const int b  = blockIdx.y;
    const int p0 = blockIdx.x << 6;
    const int t  = threadIdx.x;
    const int wv = t >> 6, l = t & 63, q = l >> 4, ln = l & 15;

    __shared__ u16 tile[32 * 66];   // [k=32][p=64] bf16, stride 66 breaks conflicts

    f32x4_t acc0 = {0.f, 0.f, 0.f, 0.f};
    f32x4_t acc1 = {0.f, 0.f, 0.f, 0.f};

    const int  sr   = t >> 3;           // staging row (k-local) 0..31
    const int  sc8  = (t & 7) << 3;     // staging col 0,8,...,56
    const bool full = (p0 + sc8 + 7) < 676;

    for (int k0 = 0; k0 < 768; k0 += 32) {
        { // stage fm[b][k0+sr][p0+sc8 .. +8) -> tile, f32 -> bf16
            const float* src = fm + (size_t)(b * 768 + k0 + sr) * 676 + p0 + sc8;
            Frag val;
            if (full) {
                load8_cvt(src, val);
            } else {
#pragma unroll
                for (int i = 0; i < 8; ++i)
                    val.s[i] = (p0 + sc8 + i < 676) ? f2b(src[i]) : (u16)0;
            }
            unsigned* dst = (unsigned*)&tile[sr * 66 + sc8];
            dst[0] = val.u[0]; dst[1] = val.u[1]; dst[2] = val.u[2]; dst[3] = val.u[3];
        }
        __syncthreads();

        Frag a0, a1, bfr;
        load8_cvt(att_w + (ln)      * 768 + k0 + q * 8, a0);
        load8_cvt(att_w + (16 + ln) * 768 + k0 + q * 8, a1);
#pragma unroll
        for (int j = 0; j < 8; ++j)
            bfr.s[j] = tile[(q * 8 + j) * 66 + wv * 16 + ln];

        acc0 = MFMA(a0.v, bfr.v, acc0);
        acc1 = MFMA(a1.v, bfr.v, acc1);
        __syncthreads();
    }

    const int p = p0 + wv * 16 + ln;   // D: col = lane&15 (within wave slice)
#pragma unroll
    for (int mt = 0; mt < 2; ++mt) {
        f32x4_t a = mt ? acc1 : acc0;
#pragma unroll
        for (int r = 0; r < 4; ++r) {
            const int m = mt * 16 + q * 4 + r;   // D: row = (lane>>4)*4 + reg
            float v = a[r] + att_b[m];
            v = v > 0.f ? v : 0.f;
            BFU hb; hb.u = f2b(v);
            att_pad[(size_t)(b * 32 + m) * 704 + p] = (p < 676) ? hb.h : (__hip_bfloat16)0.f;
            if (p < 676)
                att_out[(size_t)(b * 32 + m) * 676 + p] = v;
        }
    }
}

// ---------------- Pass 2: pooled[b] = att[b](32x704) @ fm[b]^T (704x768) / 676 ----------------
// grid (12 c-tiles, 64 b). B-frags k-contiguous in fm's native layout -> direct global loads.
__global__ __launch_bounds__(256) void k_pool(
    const float* __restrict__ fm, const u16* __restrict__ att_pad,
    float* __restrict__ pooled)
{
    const int b  = blockIdx.y;
    const int n0 = blockIdx.x << 6;
    const int t  = threadIdx.x;
    const int wv = t >> 6, l = t & 63, q = l >> 4, ln = l & 15;
    const int c  = n0 + wv * 16 + ln;

    const u16*   Ab = att_pad + (size_t)b * 32 * 704;
    const float* Bb = fm + (size_t)(b * 768 + c) * 676;

    f32x4_t acc0 = {0.f, 0.f, 0.f, 0.f};
    f32x4_t acc1 = {0.f, 0.f, 0.f, 0.f};

    for (int k0 = 0; k0 < 704; k0 += 32) {
        Frag a0, a1, bfr;
        const int k = k0 + q * 8;
        a0.u4 = *(const uint32x4*)(Ab + (ln)      * 704 + k);
        a1.u4 = *(const uint32x4*)(Ab + (16 + ln) * 704 + k);
        if (k0 < 672) {
            load8_cvt(Bb + k, bfr);
        } else {
            // tail: k=672..675 valid -> exactly one in-bounds float4; rest zero.
            bfr.u[0] = 0u; bfr.u[1] = 0u; bfr.u[2] = 0u; bfr.u[3] = 0u;
            if (q == 0) {
                f32x4_t x = *(const f32x4_t*)(Bb + 672);
#pragma unroll
                for (int j = 0; j < 4; ++j) bfr.s[j] = f2b(x[j]);
            }
        }
        acc0 = MFMA(a0.v, bfr.v, acc0);
        acc1 = MFMA(a1.v, bfr.v, acc1);
    }

    const float sc = 1.0f / 676.0f;
#pragma unroll
    for (int mt = 0; mt < 2; ++mt) {
        f32x4_t a = mt ? acc1 : acc0;
#pragma unroll
        for (int r = 0; r < 4; ++r) {
            const int m = mt * 16 + q * 4 + r;
            pooled[(size_t)(b * 32 + m) * 768 + c] = a[r] * sc;
        }
    }
}

// ---------------- Pass 3: signed sqrt + per-batch L2 normalize ----------------
// writes f32 fm_n to d_out and bf16 copy to ws (feeds k_fc's MFMA).
__global__ __launch_bounds__(256) void k_norm(
    const float* __restrict__ pooled, float* __restrict__ fm_out,
    u16* __restrict__ fmn16)
{
    const int b = blockIdx.x, t = threadIdx.x;
    const float* src = pooled + (size_t)b * 24576;

    float s = 0.f;
    for (int i = t; i < 24576; i += 256) s += fabsf(src[i]);   // sum(|x|); eps below
    for (int off = 32; off > 0; off >>= 1) s += __shfl_down(s, off);

    __shared__ float red[4];
    if ((t & 63) == 0) red[t >> 6] = s;
    __syncthreads();
    float tot = red[0] + red[1] + red[2] + red[3] + 24576.f * 1e-12f;
    float nrm = fmaxf(sqrtf(tot), 1e-12f);
    const float inv = 1.f / nrm;

    for (int i = t; i < 24576; i += 256) {
        float x = src[i];
        float v = (x == 0.f) ? 0.f : copysignf(sqrtf(fabsf(x) + 1e-12f), x);
        float o = v * inv;
        fm_out[(size_t)b * 24576 + i] = o;
        fmn16[(size_t)b * 24576 + i]  = f2b(o);
    }
}

// ---------------- Pass 4: p partials = fm_n(64x24576) @ fc_w^T, K split 16 ways ----------------
__global__ __launch_bounds__(256) void k_fc(
    const u16* __restrict__ fmn16, const float* __restrict__ fc_w,
    float* __restrict__ p_part)
{
    const int ntile = blockIdx.x;          // 0..12
    const int slab  = blockIdx.y;          // 0..15
    const int t = threadIdx.x;
    const int wv = t >> 6, l = t & 63, q = l >> 4, ln = l & 15;
    const int n = ntile * 16 + ln;
    const int kbase = slab * 1536;

    const u16*   Ab = fmn16 + (size_t)(wv * 16 + ln) * 24576 + kbase + q * 8;
    const float* Bb = fc_w + (size_t)n * 24576 + kbase + q * 8;
    const bool nok = n < 200;

    f32x4_t acc = {0.f, 0.f, 0.f, 0.f};
    for (int kk = 0; kk < 1536; kk += 32) {
        Frag af, bf2;
        af.u4 = *(const uint32x4*)(Ab + kk);
        if (nok) load8_cvt(Bb + kk, bf2);
        else { bf2.u[0] = 0u; bf2.u[1] = 0u; bf2.u[2] = 0u; bf2.u[3] = 0u; }
        acc = MFMA(af.v, bf2.v, acc);
    }
#pragma unroll
    for (int r = 0; r < 4; ++r) {
        const int bb = wv * 16 + q * 4 + r;
        p_part[(size_t)(slab * 64 + bb) * 208 + ntile * 16 + ln] = acc[r];
    }
}

// ---------------- Pass 5: reduce 16 slabs, scale 100, + bias ----------------
__global__ __launch_bounds__(256) void k_fin(
    const float* __restrict__ p_part, const float* __restrict__ fc_b,
    float* __restrict__ p_out)
{
    const int tid = blockIdx.x * 256 + threadIdx.x;   // 50*256 == 12800 exactly
    const int b = tid / 200, n = tid - b * 200;
    float s = 0.f;
#pragma unroll
    for (int sl = 0; sl < 16; ++sl) s += p_part[(size_t)(sl * 64 + b) * 208 + n];
    p_out[tid] = s * 100.f + fc_b[n];
}

extern "C" void kernel_launch(void* const* d_in, const int* in_sizes, int n_in,
                              void* d_out, int out_size, void* d_ws, size_t ws_size,
                              hipStream_t stream)
{
    const float* fm    = (const float*)d_in[0];
    const float* att_w = (const float*)d_in[1];
    const float* att_b = (const float*)d_in[2];
    const float* fc_w  = (const float*)d_in[3];
    const float* fc_b  = (const float*)d_in[4];

    float* out     = (float*)d_out;
    float* p_out   = out;                         // [64][200]
    float* fm_out  = out + 12800;                 // [64][32][768]
    float* att_out = out + 12800 + 64 * 32 * 768; // [64][32][676]

    char* ws = (char*)d_ws;
    __hip_bfloat16* att_pad = (__hip_bfloat16*)ws;        // 64*32*704*2 = 2,883,584 B
    float* pooled = (float*)(ws + 2883584);               // 64*32*768*4 = 6,291,456 B
    float* p_part = (float*)(ws + 2883584 + 6291456);     // 16*64*208*4 =   851,968 B
    u16*   fmn16  = (u16*)(ws + 2883584 + 6291456 + 851968); // 64*24576*2 = 3,145,728 B

    k_att <<<dim3(11, 64), 256, 0, stream>>>(fm, att_w, att_b, att_out, att_pad);
    k_pool<<<dim3(12, 64), 256, 0, stream>>>(fm, (const u16*)att_pad, pooled);
    k_norm<<<dim3(64),     256, 0, stream>>>(pooled, fm_out, fmn16);
    k_fc  <<<dim3(13, 16), 256, 0, stream>>>(fmn16, fc_w, p_part);
    k_fin <<<dim3(50),     256, 0, stream>>>(p_part, fc_b, p_out);
}

// Round 4
// 274.274 us; speedup vs baseline: 1.2226x; 1.2226x over previous
//
#include <hip/hip_runtime.h>
#include <hip/hip_bf16.h>

// Inputs (f32): fm [64][768][676], att_w [192][768], att_b [192],
//               fc_w [200][24576], fc_b [200]
// d_out (f32): p [64*200] | fm_n [64*32*768] | att_m [64*32*676]
// ws: {att_pad bf16 [64][32][704]  UNION  p_part f32 [48][64][208]} |
//     pooled f32 [64][32][768] | fmn16 bf16 [64*24576] | p_sums f32 [64]
// att_pad read by k_pool finishes before k_fc writes p_part -> safe overlay.
// All MFMA in bf16 (no f32 MFMA on CDNA4); 2% threshold gives ~10x margin.

typedef unsigned short u16;
typedef __bf16 bf16x8_t __attribute__((ext_vector_type(8)));
typedef float f32x4_t __attribute__((ext_vector_type(4)));
typedef unsigned int uint32x4 __attribute__((ext_vector_type(4)));

union Frag { uint32x4 u4; unsigned u[4]; u16 s[8]; bf16x8_t v; };
union BFU { __hip_bfloat16 h; u16 u; };

__device__ inline u16 f2b(float x) { BFU t; t.h = __float2bfloat16(x); return t.u; }

__device__ inline void load8_cvt(const float* p, Frag& f) {
    f32x4_t x0 = *(const f32x4_t*)(p);
    f32x4_t x1 = *(const f32x4_t*)(p + 4);
#pragma unroll
    for (int j = 0; j < 4; ++j) { f.s[j] = f2b(x0[j]); f.s[4 + j] = f2b(x1[j]); }
}

#define MFMA(a, b, c) __builtin_amdgcn_mfma_f32_16x16x32_bf16((a), (b), (c), 0, 0, 0)

// ---------------- Pass 1: att = relu(att_w[:32] @ fm[b] + att_b) ----------------
// grid (22, 64). Tile 32m x 32p. Wave wv owns K-chunk [wv*192, wv*192+192):
// no __syncthreads in the K-loop; partials combined once via LDS at the end.
// B-frags by direct per-lane loads: per instr, lanes hit 4 rows x 64B full lines.
__global__ __launch_bounds__(256) void k_att(
    const float* __restrict__ fm, const float* __restrict__ att_w,
    const float* __restrict__ att_b, float* __restrict__ att_out,
    __hip_bfloat16* __restrict__ att_pad, float* __restrict__ p_sums)
{
    const int b  = blockIdx.y;
    const int p0 = blockIdx.x << 5;          // 22 tiles of 32 -> 0..672
    const int t  = threadIdx.x;
    const int wv = t >> 6, l = t & 63, q = l >> 4, ln = l & 15;

    if (blockIdx.x == 0 && t == 0) p_sums[b] = 0.f;   // consumed by k_pool atomics

    __shared__ float red[32][32][4];   // [m][p_local][wave] f32, 16 KB

    f32x4_t acc[2][2] = {{{0.f,0.f,0.f,0.f},{0.f,0.f,0.f,0.f}},
                         {{0.f,0.f,0.f,0.f},{0.f,0.f,0.f,0.f}}};

    const int  kb   = wv * 192;
    const bool edge = (p0 == 672);           // only tile with p >= 676
    const int  pb0  = p0 + ln;
    const int  pb1  = p0 + 16 + ln;

#pragma unroll
    for (int it = 0; it < 6; ++it) {
        const int k0 = kb + it * 32;
        Frag a0, a1, b0, b1;
        load8_cvt(att_w + (size_t)ln * 768 + k0 + q * 8, a0);          // m 0..15
        load8_cvt(att_w + (size_t)(16 + ln) * 768 + k0 + q * 8, a1);   // m 16..31
        const float* base = fm + (size_t)(b * 768 + k0 + q * 8) * 676;
        if (!edge) {
#pragma unroll
            for (int j = 0; j < 8; ++j) {
                b0.s[j] = f2b(base[(size_t)j * 676 + pb0]);
                b1.s[j] = f2b(base[(size_t)j * 676 + pb1]);
            }
        } else {
#pragma unroll
            for (int j = 0; j < 8; ++j) {
                b0.s[j] = (pb0 < 676) ? f2b(base[(size_t)j * 676 + pb0]) : (u16)0;
                b1.s[j] = (u16)0;    // pb1 >= 688 always on edge tile
            }
        }
        acc[0][0] = MFMA(a0.v, b0.v, acc[0][0]);
        acc[0][1] = MFMA(a0.v, b1.v, acc[0][1]);
        acc[1][0] = MFMA(a1.v, b0.v, acc[1][0]);
        acc[1][1] = MFMA(a1.v, b1.v, acc[1][1]);
    }

#pragma unroll
    for (int mh = 0; mh < 2; ++mh)
#pragma unroll
        for (int ph = 0; ph < 2; ++ph)
#pragma unroll
            for (int r = 0; r < 4; ++r)
                red[mh * 16 + q * 4 + r][ph * 16 + ln][wv] = acc[mh][ph][r];
    __syncthreads();

    const int m = t >> 3, c0 = (t & 7) << 2;
#pragma unroll
    for (int j = 0; j < 4; ++j) {
        const int pl = c0 + j;
        f32x4_t v4 = *(const f32x4_t*)&red[m][pl][0];
        float v = v4[0] + v4[1] + v4[2] + v4[3] + att_b[m];
        v = v > 0.f ? v : 0.f;
        const int p = p0 + pl;
        BFU hb; hb.u = f2b(v);
        att_pad[(size_t)(b * 32 + m) * 704 + p] = (p < 676) ? hb.h : (__hip_bfloat16)0.f;
        if (p < 676)
            att_out[(size_t)(b * 32 + m) * 676 + p] = v;
    }
}

// ---------------- Pass 2: pooled[b] = att[b](32x704) @ fm[b]^T / 676 ----------------
// grid (24, 64). Tile 32m x 32c. 22 k-steps striped across the 4 waves
// (it = wv, wv+4, ...), no barriers in loop; LDS combine at end. Also fuses the
// Sum|pooled| reduction: one atomicAdd per block into p_sums[b].
__global__ __launch_bounds__(256) void k_pool(
    const float* __restrict__ fm, const u16* __restrict__ att_pad,
    float* __restrict__ pooled, float* __restrict__ p_sums)
{
    const int b  = blockIdx.y;
    const int n0 = blockIdx.x << 5;          // 24 tiles of 32
    const int t  = threadIdx.x;
    const int wv = t >> 6, l = t & 63, q = l >> 4, ln = l & 15;

    __shared__ float red[32][32][4];
    __shared__ float rs[4];

    const u16*   Ab = att_pad + (size_t)b * 32 * 704;
    const float* B0 = fm + (size_t)(b * 768 + n0 + ln) * 676;
    const float* B1 = fm + (size_t)(b * 768 + n0 + 16 + ln) * 676;

    f32x4_t acc[2][2] = {{{0.f,0.f,0.f,0.f},{0.f,0.f,0.f,0.f}},
                         {{0.f,0.f,0.f,0.f},{0.f,0.f,0.f,0.f}}};

    for (int it = wv; it < 22; it += 4) {
        const int k = it * 32 + q * 8;
        Frag a0, a1, b0, b1;
        a0.u4 = *(const uint32x4*)(Ab + (size_t)ln * 704 + k);
        a1.u4 = *(const uint32x4*)(Ab + (size_t)(16 + ln) * 704 + k);
        if (it < 21) {
            load8_cvt(B0 + k, b0);
            load8_cvt(B1 + k, b1);
        } else {
            // k0=672: only p=672..675 valid (att_pad cols >=676 are zero anyway).
            b0.u[0]=0u; b0.u[1]=0u; b0.u[2]=0u; b0.u[3]=0u;
            b1.u[0]=0u; b1.u[1]=0u; b1.u[2]=0u; b1.u[3]=0u;
            if (q == 0) {
                f32x4_t x0 = *(const f32x4_t*)(B0 + 672);
                f32x4_t x1 = *(const f32x4_t*)(B1 + 672);
#pragma unroll
                for (int j = 0; j < 4; ++j) { b0.s[j] = f2b(x0[j]); b1.s[j] = f2b(x1[j]); }
            }
        }
        acc[0][0] = MFMA(a0.v, b0.v, acc[0][0]);
        acc[0][1] = MFMA(a0.v, b1.v, acc[0][1]);
        acc[1][0] = MFMA(a1.v, b0.v, acc[1][0]);
        acc[1][1] = MFMA(a1.v, b1.v, acc[1][1]);
    }

#pragma unroll
    for (int mh = 0; mh < 2; ++mh)
#pragma unroll
        for (int ch = 0; ch < 2; ++ch)
#pragma unroll
            for (int r = 0; r < 4; ++r)
                red[mh * 16 + q * 4 + r][ch * 16 + ln][wv] = acc[mh][ch][r];
    __syncthreads();

    const float sc = 1.0f / 676.0f;
    const int m = t >> 3, c0 = (t & 7) << 2;
    float ls = 0.f;
#pragma unroll
    for (int j = 0; j < 4; ++j) {
        const int cl = c0 + j;
        f32x4_t v4 = *(const f32x4_t*)&red[m][cl][0];
        float v = (v4[0] + v4[1] + v4[2] + v4[3]) * sc;
        pooled[(size_t)(b * 32 + m) * 768 + n0 + cl] = v;
        ls += fabsf(v);
    }
    for (int off = 32; off > 0; off >>= 1) ls += __shfl_down(ls, off);
    if (l == 0) rs[wv] = ls;
    __syncthreads();
    if (t == 0) atomicAdd(p_sums + b, rs[0] + rs[1] + rs[2] + rs[3]);
}

// ---------------- Pass 3 (apply only): signed sqrt + L2 normalize ----------------
// norm^2 = Sum(|x|+eps) = p_sums[b] + N*eps. grid (64, 12), 2048 elems/block.
__global__ __launch_bounds__(256) void k_norm(
    const float* __restrict__ pooled, const float* __restrict__ p_sums,
    float* __restrict__ fm_out, u16* __restrict__ fmn16)
{
    const int b = blockIdx.x;
    const size_t base = (size_t)b * 24576 + (size_t)blockIdx.y * 2048;
    const float tot = p_sums[b] + 24576.f * 1e-12f;
    const float inv = 1.f / fmaxf(sqrtf(tot), 1e-12f);
    const int t = threadIdx.x;
#pragma unroll
    for (int i = 0; i < 8; ++i) {
        const size_t idx = base + i * 256 + t;
        float x = pooled[idx];
        float v = (x == 0.f) ? 0.f : copysignf(sqrtf(fabsf(x) + 1e-12f), x);
        float o = v * inv;
        fm_out[idx] = o;
        fmn16[idx]  = f2b(o);
    }
}

// ---------------- Pass 4: p partials, K=24576 split into 48 slabs of 512 ----------------
__global__ __launch_bounds__(256) void k_fc(
    const u16* __restrict__ fmn16, const float* __restrict__ fc_w,
    float* __restrict__ p_part)
{
    const int ntile = blockIdx.x;          // 0..12
    const int slab  = blockIdx.y;          // 0..47
    const int t = threadIdx.x;
    const int wv = t >> 6, l = t & 63, q = l >> 4, ln = l & 15;
    const int n = ntile * 16 + ln;
    const int kbase = slab * 512;

    const u16*   Ab = fmn16 + (size_t)(wv * 16 + ln) * 24576 + kbase + q * 8;
    const float* Bb = fc_w + (size_t)n * 24576 + kbase + q * 8;
    const bool nok = n < 200;

    f32x4_t acc = {0.f, 0.f, 0.f, 0.f};
#pragma unroll
    for (int kk = 0; kk < 512; kk += 32) {
        Frag af, bf2;
        af.u4 = *(const uint32x4*)(Ab + kk);
        if (nok) load8_cvt(Bb + kk, bf2);
        else { bf2.u[0] = 0u; bf2.u[1] = 0u; bf2.u[2] = 0u; bf2.u[3] = 0u; }
        acc = MFMA(af.v, bf2.v, acc);
    }
#pragma unroll
    for (int r = 0; r < 4; ++r) {
        const int bb = wv * 16 + q * 4 + r;
        p_part[(size_t)(slab * 64 + bb) * 208 + ntile * 16 + ln] = acc[r];
    }
}

// ---------------- Pass 5: reduce 48 slabs, scale 100, + bias ----------------
__global__ __launch_bounds__(256) void k_fin(
    const float* __restrict__ p_part, const float* __restrict__ fc_b,
    float* __restrict__ p_out)
{
    const int tid = blockIdx.x * 256 + threadIdx.x;   // 50*256 == 12800
    const int b = tid / 200, n = tid - b * 200;
    float s = 0.f;
#pragma unroll
    for (int sl = 0; sl < 48; ++sl) s += p_part[(size_t)(sl * 64 + b) * 208 + n];
    p_out[tid] = s * 100.f + fc_b[n];
}

extern "C" void kernel_launch(void* const* d_in, const int* in_sizes, int n_in,
                              void* d_out, int out_size, void* d_ws, size_t ws_size,
                              hipStream_t stream)
{
    const float* fm    = (const float*)d_in[0];
    const float* att_w = (const float*)d_in[1];
    const float* att_b = (const float*)d_in[2];
    const float* fc_w  = (const float*)d_in[3];
    const float* fc_b  = (const float*)d_in[4];

    float* out     = (float*)d_out;
    float* p_out   = out;                         // [64][200]
    float* fm_out  = out + 12800;                 // [64][32][768]
    float* att_out = out + 12800 + 64 * 32 * 768; // [64][32][676]

    char* ws = (char*)d_ws;
    // att_pad (2,883,584 B) and p_part (2,555,904 B) have disjoint lifetimes -> overlay.
    __hip_bfloat16* att_pad = (__hip_bfloat16*)ws;
    float* p_part = (float*)ws;
    float* pooled = (float*)(ws + 2883584);               // 6,291,456 B
    u16*   fmn16  = (u16*)(ws + 2883584 + 6291456);       // 3,145,728 B
    float* p_sums = (float*)(ws + 2883584 + 6291456 + 3145728); // 256 B  (total 12.3 MB)

    k_att <<<dim3(22, 64), 256, 0, stream>>>(fm, att_w, att_b, att_out, att_pad, p_sums);
    k_pool<<<dim3(24, 64), 256, 0, stream>>>(fm, (const u16*)att_pad, pooled, p_sums);
    k_norm<<<dim3(64, 12), 256, 0, stream>>>(pooled, p_sums, fm_out, fmn16);
    k_fc  <<<dim3(13, 48), 256, 0, stream>>>(fmn16, fc_w, p_part);
    k_fin <<<dim3(50),     256, 0, stream>>>(p_part, fc_b, p_out);
}